// Round 1
// 396.973 us; speedup vs baseline: 1.0969x; 1.0969x over previous
//
#include <hip/hip_runtime.h>

#define T_ 32
#define B_ 32
#define MAPD 517
#define P_ 256
#define FLATD (MAPD*P_)   // 132352
#define TBN (T_*B_)       // 1024

typedef unsigned short u16;
typedef unsigned int u32;
typedef __attribute__((ext_vector_type(4))) short short4v;
typedef __attribute__((ext_vector_type(8))) short short8v;
typedef __attribute__((ext_vector_type(4))) float f32x4;

__device__ __forceinline__ float bfv(u16 u){ u32 x = ((u32)u)<<16; return __uint_as_float(x); }
__device__ __forceinline__ u16 fbf(float f){
  u32 x = __float_as_uint(f);
  return (u16)((x + 0x7fffu + ((x>>16)&1u))>>16);
}
template<bool F32> __device__ __forceinline__ float ld(const void* p, size_t i){
  if constexpr (F32) return ((const float*)p)[i];
  else               return bfv(((const u16*)p)[i]);
}

// ---- dtype probe: 1 if float inputs are fp32, 0 if bf16 ----
__global__ void k_probe(const void* img, int* flag){
  if (threadIdx.x == 0 && blockIdx.x == 0){
    const u16* u = (const u16*)img;
    int cnt = 0;
    for (int i = 0; i < 256; ++i) if (u[i] <= 0x4380u) ++cnt;
    *flag = (cnt < 240) ? 1 : 0;
  }
}

// ---- K-prep (fused): conv frag layouts + FWF (fc MFMA B-frags) + ST0T transpose ----
__global__ __launch_bounds__(256) void k_prep(const void* c1w, const void* c2w, const void* c3w,
                                              const void* fcw, const void* st0,
                                              u16* W1F, u16* W2F, u16* W3F, u16* FWF, u16* ST0T,
                                              const int* flag){
  __shared__ __align__(16) char smem_[32768];
  bool f32 = (*flag != 0);
  int bid = blockIdx.x, tid = threadIdx.x;
  if (bid < 24){
    int idx = bid*256 + tid;                   // 6144
    int j = idx & 7, l = (idx>>3) & 63, t = idx>>9;
    int nt = t/6, s = t - nt*6;
    int oc = nt*16 + (l&15);
    int kk = 8*(4*s + (l>>4)) + j;
    float v = f32 ? ((const float*)c1w)[oc*192+kk] : bfv(((const u16*)c1w)[oc*192+kk]);
    W1F[idx] = fbf(v);
  } else if (bid < 152){
    int idx = (bid-24)*256 + tid;              // 32768
    int j = idx & 7, l = (idx>>3) & 63, s = (idx>>9) & 15, nt = idx>>13;
    int oc = nt*16 + (l&15);
    int cin = (l>>4)*8 + j;
    int src = oc*512 + cin*16 + (s>>2)*4 + (s&3);
    float v = f32 ? ((const float*)c2w)[src] : bfv(((const u16*)c2w)[src]);
    W2F[idx] = fbf(v);
  } else if (bid < 296){
    int idx = (bid-152)*256 + tid;             // 36864
    int j = idx & 7, l = (idx>>3) & 63, t = idx>>9;   // t = nt*18+s
    int nt = t/18, s = t - nt*18;
    int oc = nt*16 + (l&15);
    int c = (s&1)*32 + (l>>4)*8 + j;
    int src = oc*576 + c*9 + (s>>1);
    float v = f32 ? ((const float*)c3w)[src] : bfv(((const u16*)c3w)[src]);
    W3F[idx] = fbf(v);
  } else if (bid < 424){
    // FWF: MFMA B-fragments of fc_w for k_fc.
    //   frag = nt*32 + kt (nt: 16-wide o-tile, kt: 32-deep k-step)
    //   FWF[(frag*64 + l)*8 + j] = fcw[o = nt*16+(l&15)][k_ref]
    //   k_C = kt*32 + (l>>4)*8 + j  (conv3 output order: pos*64+oc)
    //   k_ref = (k_C & 63)*16 + (k_C >> 6)  (reference flatten order: oc*16+pos)
    int b = bid - 296;                          // 128 blocks x 4096 elems
    for (int it = 0; it < 16; ++it){
      int idx = (b*16 + it)*256 + tid;          // 524288 total
      int j = idx & 7, l = (idx>>3) & 63, frag = idx >> 9;
      int nt = frag >> 5, kt = frag & 31;
      int kc = kt*32 + ((l>>4)<<3) + j;
      int kr = (kc & 63)*16 + (kc >> 6);
      int o  = nt*16 + (l & 15);
      float v = f32 ? ((const float*)fcw)[(size_t)o*1024 + kr]
                    : bfv(((const u16*)fcw)[(size_t)o*1024 + kr]);
      FWF[idx] = fbf(v);
    }
  } else {
    // ST0T[p][c][b] transpose
    u16* tile = (u16*)smem_;                   // 32,768 B
    int b0 = bid - 424;                        // 260 blocks
    int c0 = (b0 >> 2)*8, p0 = (b0 & 3)*64;
    for (int it = 0; it < 64; ++it){
      int idx = it*256 + tid;
      int pl = idx & 63, b = (idx>>6)&31, ci = idx>>11;
      int c = c0 + ci;
      float v = 0.f;
      if (c < MAPD)
        v = f32 ? ((const float*)st0)[((size_t)b*MAPD+c)*256 + p0+pl]
                : bfv(((const u16*)st0)[((size_t)b*MAPD+c)*256 + p0+pl]);
      tile[ci*2048 + pl*32 + b] = fbf(v);
    }
    __syncthreads();
    for (int it = 0; it < 64; ++it){
      int idx = it*256 + tid;
      int b = idx & 31, ci = (idx>>5)&7, pl = idx>>8;
      int c = c0 + ci;
      if (c < MAPD)
        ST0T[((size_t)(p0+pl)*MAPD + c)*32 + b] = tile[ci*2048 + pl*32 + b];
    }
  }
}

// ---- K-meta (fused): prev-writer/coef + one-hot into H ; last-writer/coef ----
__global__ void k_meta(const int* pos, const void* done, const int* lact,
                       int* prev, float* coef, float* H, int* lastw, float* lastc, const int* flag){
  bool f32 = (*flag != 0);
  int bid = blockIdx.x;
  if (bid < 4){
    int i = bid*256 + threadIdx.x;
    int t = i >> 5, b = i & 31;
    int p = pos[i*2]*16 + pos[i*2+1];
    int pv = -1;
    for (int s = t-1; s >= 0; --s){
      int n = s*32 + b;
      if (pos[n*2]*16 + pos[n*2+1] == p){ pv = s; break; }
    }
    float cf = 1.f;
    for (int s = (pv<0?0:pv+1); s <= t-1; ++s)
      cf *= (1.f - (f32 ? ((const float*)done)[s*32+b] : bfv(((const u16*)done)[s*32+b])));
    prev[i] = pv; coef[i] = cf;
    int la = lact[i];
    #pragma unroll
    for (int a = 0; a < 5; ++a) H[(size_t)i*MAPD + 512 + a] = (la == a) ? 1.f : 0.f;
  } else {
    int i = (bid-4)*256 + threadIdx.x;
    int b = i >> 8, p = i & 255;
    int lw = -1;
    for (int s = T_-1; s >= 0; --s){
      int n = s*32 + b;
      if (pos[n*2]*16 + pos[n*2+1] == p){ lw = s; break; }
    }
    float cf = 1.f;
    for (int s = (lw<0?0:lw+1); s < T_; ++s)
      cf *= (1.f - (f32 ? ((const float*)done)[s*32+b] : bfv(((const u16*)done)[s*32+b])));
    lastw[i] = lw; lastc[i] = cf;
  }
}

// ---- K1: conv1 MFMA implicit GEMM. M=225 (16 tiles), N=32 (2 tiles), K=192 (6 steps) ----
__global__ __launch_bounds__(256) void k_conv1(const void* img, const u16* W1F, const void* bias,
                                               u16* out, const int* flag){
  __shared__ u16 sImg[12288];
  __shared__ u16 sWF[6144];
  __shared__ float sB[32];
  bool f32 = (*flag != 0);
  int n = blockIdx.x, tid = threadIdx.x;
  if (f32){
    const float4* ip = (const float4*)((const float*)img + (size_t)n*12288);
    for (int i = tid; i < 3072; i += 256){
      float4 v = ip[i];
      ushort4 u; u.x = fbf(v.x); u.y = fbf(v.y); u.z = fbf(v.z); u.w = fbf(v.w);
      *(ushort4*)(sImg + i*4) = u;
    }
  } else {
    const ushort4* ip = (const ushort4*)((const u16*)img + (size_t)n*12288);
    for (int i = tid; i < 3072; i += 256) *(ushort4*)(sImg + i*4) = ip[i];
  }
  { const ushort4* wf = (const ushort4*)W1F;
    for (int i = tid; i < 1536; i += 256) *(ushort4*)(sWF + i*4) = wf[i]; }
  if (tid < 32) sB[tid] = f32 ? ((const float*)bias)[tid] : bfv(((const u16*)bias)[tid]);
  __syncthreads();

  int wv = tid >> 6, lane = tid & 63;
  int mi = lane & 15, q = lane >> 4;

  short8v bfr[2][6];
  #pragma unroll
  for (int nt = 0; nt < 2; ++nt)
    #pragma unroll
    for (int s = 0; s < 6; ++s)
      bfr[nt][s] = *(const short8v*)(sWF + ((nt*6+s)*64 + lane)*8);

  f32x4 acc[4][2];
  #pragma unroll
  for (int mt = 0; mt < 4; ++mt)
    #pragma unroll
    for (int nt = 0; nt < 2; ++nt)
      acc[mt][nt] = (f32x4){0.f,0.f,0.f,0.f};

  int base[4];
  #pragma unroll
  for (int mt = 0; mt < 4; ++mt){
    int m = (wv*4+mt)*16 + mi;
    int mc = m < 225 ? m : 224;
    int oy = mc/15, ox = mc - oy*15;
    base[mt] = oy*256 + ox*4;
  }

  for (int s = 0; s < 6; ++s){
    int cky = 4*s + q;
    int off = (cky >> 3)*4096 + (cky & 7)*64;
    #pragma unroll
    for (int mt = 0; mt < 4; ++mt){
      const u16* ap = sImg + base[mt] + off;
      short4v lo = *(const short4v*)ap;
      short4v hi = *(const short4v*)(ap + 4);
      short8v a = __builtin_shufflevector(lo, hi, 0,1,2,3,4,5,6,7);
      acc[mt][0] = __builtin_amdgcn_mfma_f32_16x16x32_bf16(a, bfr[0][s], acc[mt][0], 0,0,0);
      acc[mt][1] = __builtin_amdgcn_mfma_f32_16x16x32_bf16(a, bfr[1][s], acc[mt][1], 0,0,0);
    }
  }

  u16* ob = out + (size_t)n*7200;
  #pragma unroll
  for (int mt = 0; mt < 4; ++mt){
    int mrow0 = (wv*4+mt)*16 + q*4;
    #pragma unroll
    for (int nt = 0; nt < 2; ++nt){
      int oc = nt*16 + mi;
      float bv = sB[oc];
      #pragma unroll
      for (int r = 0; r < 4; ++r){
        int m = mrow0 + r;
        if (m < 225) ob[m*32 + oc] = fbf(fmaxf(acc[mt][nt][r] + bv, 0.f));
      }
    }
  }
}

// ---- K2: conv2 MFMA implicit GEMM ----
__global__ __launch_bounds__(256) void k_conv2(const u16* __restrict__ A, const u16* __restrict__ W2F,
                                               const void* bias, u16* __restrict__ out, const int* flag){
  __shared__ u16 sIn[7200];
  bool f32 = (*flag != 0);
  int n = blockIdx.x, tid = threadIdx.x;
  const ushort4* ip = (const ushort4*)(A + (size_t)n*7200);
  for (int i = tid; i < 1800; i += 256) *(ushort4*)(sIn + i*4) = ip[i];
  int wv = tid >> 6, lane = tid & 63, mi = lane & 15, q = lane >> 4;

  short8v bfr[16];
  #pragma unroll
  for (int s = 0; s < 16; ++s)
    bfr[s] = ((const short8v*)W2F)[(wv*16+s)*64 + lane];

  int oc = wv*16 + mi;
  float bv = f32 ? ((const float*)bias)[oc] : bfv(((const u16*)bias)[oc]);
  f32x4 acc[3];
  #pragma unroll
  for (int mt = 0; mt < 3; ++mt) acc[mt] = (f32x4){0.f,0.f,0.f,0.f};
  int base[3];
  #pragma unroll
  for (int mt = 0; mt < 3; ++mt){
    int m = mt*16 + mi; if (m > 35) m = 35;
    int oy = m/6, ox = m - oy*6;
    base[mt] = (oy*30 + ox*2)*32;
  }
  __syncthreads();
  #pragma unroll
  for (int s = 0; s < 16; ++s){
    int off = ((s>>2)*15 + (s&3))*32 + q*8;
    #pragma unroll
    for (int mt = 0; mt < 3; ++mt){
      short8v a = *(const short8v*)(sIn + base[mt] + off);
      acc[mt] = __builtin_amdgcn_mfma_f32_16x16x32_bf16(a, bfr[s], acc[mt], 0,0,0);
    }
  }
  u16* ob = out + (size_t)n*2304;
  #pragma unroll
  for (int mt = 0; mt < 3; ++mt)
    #pragma unroll
    for (int r = 0; r < 4; ++r){
      int m = mt*16 + q*4 + r;
      if (m < 36) ob[m*64 + oc] = fbf(fmaxf(acc[mt][r] + bv, 0.f));
    }
}

// ---- K3: conv3 MFMA implicit GEMM ----
__global__ __launch_bounds__(256) void k_conv3(const u16* __restrict__ Bv, const u16* __restrict__ W3F,
                                               const void* bias, u16* __restrict__ out, const int* flag){
  __shared__ u16 sIn[2304];
  bool f32 = (*flag != 0);
  int n = blockIdx.x, tid = threadIdx.x;
  const ushort4* ip = (const ushort4*)(Bv + (size_t)n*2304);
  for (int i = tid; i < 576; i += 256) *(ushort4*)(sIn + i*4) = ip[i];
  int wv = tid >> 6, lane = tid & 63, mi = lane & 15, q = lane >> 4;
  int oy = mi >> 2, ox = mi & 3;
  int oc = wv*16 + mi;
  float bv = f32 ? ((const float*)bias)[oc] : bfv(((const u16*)bias)[oc]);

  short8v bfr[18];
  #pragma unroll
  for (int s = 0; s < 18; ++s)
    bfr[s] = ((const short8v*)W3F)[(wv*18+s)*64 + lane];

  f32x4 acc = (f32x4){0.f,0.f,0.f,0.f};
  __syncthreads();
  #pragma unroll
  for (int s = 0; s < 18; ++s){
    int pair = s >> 1, ky = pair/3, kx = pair - ky*3;
    int off = ((oy+ky)*6 + ox+kx)*64 + (s&1)*32 + q*8;
    short8v a = *(const short8v*)(sIn + off);
    acc = __builtin_amdgcn_mfma_f32_16x16x32_bf16(a, bfr[s], acc, 0,0,0);
  }
  u16* ob = out + (size_t)n*1024;
  #pragma unroll
  for (int r = 0; r < 4; ++r)
    ob[(q*4+r)*64 + oc] = fbf(fmaxf(acc[r] + bv, 0.f));
}

// ---- K4: fc MFMA GEMM 1024x512x1024 + ReLU -> H[samp][517] fp32 ----
// grid 512 = 64 m-tiles x 8 n-groups; 4 waves/block, one 16-col n-tile per wave.
// A frags straight from C (row-major, K contiguous); B frags coalesced from FWF.
__global__ __launch_bounds__(256) void k_fc(const u16* __restrict__ C, const u16* __restrict__ FWF,
                                            const void* fb, float* __restrict__ H, const int* flag){
  bool f32 = (*flag != 0);
  int wv = threadIdx.x >> 6, lane = threadIdx.x & 63;
  int mi = lane & 15, q = lane >> 4;
  int mt = blockIdx.x >> 3;               // 0..63
  int nt = (blockIdx.x & 7)*4 + wv;       // 0..31
  const u16* ap = C + (size_t)(mt*16 + mi)*1024 + q*8;
  const short8v* bp = (const short8v*)FWF + (size_t)nt*32*64 + lane;
  f32x4 acc0 = (f32x4){0.f,0.f,0.f,0.f};
  f32x4 acc1 = (f32x4){0.f,0.f,0.f,0.f};
  #pragma unroll
  for (int kt = 0; kt < 32; kt += 2){
    short8v a0 = *(const short8v*)(ap + kt*32);
    short8v b0 = bp[kt*64];
    short8v a1 = *(const short8v*)(ap + (kt+1)*32);
    short8v b1 = bp[(kt+1)*64];
    acc0 = __builtin_amdgcn_mfma_f32_16x16x32_bf16(a0, b0, acc0, 0,0,0);
    acc1 = __builtin_amdgcn_mfma_f32_16x16x32_bf16(a1, b1, acc1, 0,0,0);
  }
  int o = nt*16 + mi;
  float bv = f32 ? ((const float*)fb)[o] : bfv(((const u16*)fb)[o]);
  #pragma unroll
  for (int r = 0; r < 4; ++r){
    int m = mt*16 + q*4 + r;
    H[(size_t)m*MAPD + o] = fmaxf(acc0[r] + acc1[r] + bv, 0.f);
  }
}

// ---- K0: transpose w1 (128 x 132352) into WT[p][c][j] bf16 ----
template<bool F32> __device__ void wt_body(const void* pw1, const void* vw1, u16* wt, u16* tile){
  int c  = blockIdx.x >> 1;
  int ph = blockIdx.x & 1;
  for (int idx = threadIdx.x; idx < 16384; idx += 256){
    int j = idx >> 7, pp = idx & 127;
    const void* w = (j < 64) ? pw1 : vw1;
    int jj = (j < 64) ? j : j - 64;
    tile[pp*129 + j] = fbf(ld<F32>(w, (size_t)jj*FLATD + c*P_ + ph*128 + pp));
  }
  __syncthreads();
  for (int idx = threadIdx.x; idx < 16384; idx += 256){
    int pp = idx >> 7, j = idx & 127;
    int p = ph*128 + pp;
    wt[((size_t)p*MAPD + c)*128 + j] = tile[pp*129 + j];
  }
}
__global__ __launch_bounds__(256) void k_wt(const void* pw1, const void* vw1, u16* wt, const int* flag){
  __shared__ u16 tile[128*129];
  if (*flag) wt_body<true>(pw1,vw1,wt,tile); else wt_body<false>(pw1,vw1,wt,tile);
}

// ---- K6: y_init partials: PARTB[block][b][j] (bf16), no atomics ----
template<int CLEN>
__device__ __forceinline__ void yloop(const u16* __restrict__ wp, const float* __restrict__ sSb,
                                      float (&acc)[8][2]){
  #pragma unroll 10
  for (int c = 0; c < CLEN; ++c){
    u32 w = *(const u32*)(wp + (size_t)c*128);            // global, 256 B/wave, L1-shared
    float w0 = bfv((u16)(w & 0xffffu)), w1 = bfv((u16)(w >> 16));
    const float4* s4 = (const float4*)(sSb + c*32);       // LDS broadcast (free)
    float4 sa = s4[0], sb = s4[1];
    float sv[8] = {sa.x,sa.y,sa.z,sa.w,sb.x,sb.y,sb.z,sb.w};
    #pragma unroll
    for (int bb = 0; bb < 8; ++bb){
      acc[bb][0] += sv[bb]*w0;
      acc[bb][1] += sv[bb]*w1;
    }
  }
}
__global__ __launch_bounds__(256) void k_yinit(const u16* __restrict__ ST0T, const u16* __restrict__ wt,
                                               u16* __restrict__ PARTB){
  __shared__ float sS[130*32];   // 16.6 KB -> high occupancy
  int p = blockIdx.x >> 2, cq = blockIdx.x & 3;
  int c0 = cq*130;
  int clen = (cq == 3) ? 127 : 130;
  const ushort4* ssrc = (const ushort4*)(ST0T + ((size_t)p*MAPD + c0)*32);
  int n4 = clen*8;
  for (int i = threadIdx.x; i < n4; i += 256){
    ushort4 u = ssrc[i];
    float4 f; f.x = bfv(u.x); f.y = bfv(u.y); f.z = bfv(u.z); f.w = bfv(u.w);
    *(float4*)(sS + i*4) = f;
  }
  __syncthreads();
  int jg = threadIdx.x & 63, bg = threadIdx.x >> 6;
  int j0 = jg*2, b0 = bg*8;
  const u16* wp = wt + ((size_t)p*MAPD + c0)*128 + j0;
  float acc[8][2] = {};
  if (cq < 3) yloop<130>(wp, sS + b0, acc);
  else        yloop<127>(wp, sS + b0, acc);
  u32* op = (u32*)(PARTB + (size_t)blockIdx.x*4096);
  #pragma unroll
  for (int bb = 0; bb < 8; ++bb){
    u32 pk = (u32)fbf(acc[bb][0]) | ((u32)fbf(acc[bb][1]) << 16);
    op[((b0+bb)*128 + j0) >> 1] = pk;
  }
}

// ---- K6b: reduce 1024 partials -> YI (fp32) ----
__global__ __launch_bounds__(256) void k_yred(const u16* __restrict__ PARTB, float* __restrict__ YI){
  int o = blockIdx.x*64 + (threadIdx.x & 63);
  int kq = threadIdx.x >> 6;
  float s = 0.f;
  const u16* pp = PARTB + (size_t)kq*256*4096 + o;
  #pragma unroll 8
  for (int k = 0; k < 256; ++k) s += bfv(pp[(size_t)k*4096]);
  __shared__ float red[256];
  red[threadIdx.x] = s;
  __syncthreads();
  if (threadIdx.x < 64)
    YI[o] = red[threadIdx.x] + red[threadIdx.x+64] + red[threadIdx.x+128] + red[threadIdx.x+192];
}

// ---- K7: delta partial dots; grid (n x 4 c-chunks) -> DLT4[n*4+cq][j] ----
__global__ __launch_bounds__(128) void k_delta(const float* __restrict__ H, const u16* __restrict__ wt,
                                               const u16* __restrict__ st0t,
                                               const int* __restrict__ pos, const void* done,
                                               const int* __restrict__ prev, const float* __restrict__ coef,
                                               float* __restrict__ dlt4, const int* flag){
  __shared__ float diff[132];
  bool f32 = (*flag != 0);
  int n = blockIdx.x >> 2, cq = blockIdx.x & 3;
  int c0 = cq*130, clen = (cq == 3) ? 127 : 130;
  int b = n & 31;
  int p = pos[n*2]*16 + pos[n*2+1];
  float dn = f32 ? ((const float*)done)[n] : bfv(((const u16*)done)[n]);
  float m = 1.f - dn;
  int pv = prev[n];
  float cf = coef[n]*m;
  const float* hc = H + (size_t)n*MAPD + c0;
  for (int c = threadIdx.x; c < clen; c += 128){
    float old;
    if (pv >= 0) old = H[(size_t)(pv*32 + b)*MAPD + c0 + c];
    else         old = bfv(st0t[((size_t)p*MAPD + c0 + c)*32 + b]);
    diff[c] = hc[c] - cf*old;
  }
  __syncthreads();
  int j = threadIdx.x;
  const u16* wp = wt + ((size_t)p*MAPD + c0)*128 + j;
  float acc = 0.f;
  int c = 0;
  for (; c + 4 <= clen; c += 4){
    u16 w0 = wp[(size_t)c*128], w1 = wp[(size_t)(c+1)*128];
    u16 w2 = wp[(size_t)(c+2)*128], w3 = wp[(size_t)(c+3)*128];
    acc += diff[c]*bfv(w0) + diff[c+1]*bfv(w1) + diff[c+2]*bfv(w2) + diff[c+3]*bfv(w3);
  }
  for (; c < clen; ++c) acc += diff[c]*bfv(wp[(size_t)c*128]);
  dlt4[(size_t)blockIdx.x*128 + j] = acc;
}

// ---- K8: 32-step scan + head matvecs (sums 4 delta partials) ----
template<bool F32> __device__ void scan_body(const float* yi, const float* dlt4, const void* done,
                                             const void* pb1, const void* vb1,
                                             const void* pw2, const void* pb2,
                                             const void* vw2, const void* vb2, void* out,
                                             float* th){
  int b = blockIdx.x, j = threadIdx.x;
  float y = yi[b*128 + j];
  float bias = (j < 64) ? ld<F32>(pb1, j) : ld<F32>(vb1, j-64);
  for (int t = 0; t < T_; ++t){
    int n = t*32 + b;
    float m = 1.f - ld<F32>(done, n);
    const float* dp = dlt4 + (size_t)n*4*128 + j;
    float d = dp[0] + dp[128] + dp[256] + dp[384];
    y = m*y + d;
    th[j] = tanhf(y + bias);
    __syncthreads();
    if (j < 5){
      float s = ld<F32>(pb2, j);
      for (int q = 0; q < 64; ++q) s += th[q]*ld<F32>(pw2, j*64 + q);
      if constexpr (F32) ((float*)out)[n*5 + j] = s; else ((u16*)out)[n*5 + j] = fbf(s);
    } else if (j == 5){
      float s = ld<F32>(vb2, 0);
      for (int q = 0; q < 64; ++q) s += th[64 + q]*ld<F32>(vw2, q);
      if constexpr (F32) ((float*)out)[5120 + n] = s; else ((u16*)out)[5120 + n] = fbf(s);
    }
    __syncthreads();
  }
}
__global__ __launch_bounds__(128) void k_scan(const float* yi, const float* dlt4, const void* done,
                                              const void* pb1, const void* vb1,
                                              const void* pw2, const void* pb2,
                                              const void* vw2, const void* vb2, void* out,
                                              const int* flag){
  __shared__ float th[128];
  if (*flag) scan_body<true>(yi,dlt4,done,pb1,vb1,pw2,pb2,vw2,vb2,out,th);
  else       scan_body<false>(yi,dlt4,done,pb1,vb1,pw2,pb2,vw2,vb2,out,th);
}

// ---- K9: final_state closed form ----
template<bool F32> __device__ void final_body(const float* H, const void* st0,
                                              const int* lastw, const float* lastc, void* out){
  size_t i = (size_t)blockIdx.x*256 + threadIdx.x;
  if (i >= (size_t)B_*FLATD) return;
  int b = (int)(i / FLATD);
  int r = (int)(i - (size_t)b*FLATD);
  int c = r >> 8, p = r & 255;
  int lw = lastw[b*256 + p];
  float lc = lastc[b*256 + p];
  float v;
  if (lw >= 0) v = H[(size_t)(lw*32 + b)*MAPD + c]*lc;
  else         v = ld<F32>(st0, i)*lc;
  if constexpr (F32) ((float*)out)[6144 + i] = v; else ((u16*)out)[6144 + i] = fbf(v);
}
__global__ __launch_bounds__(256) void k_final(const float* H, const void* st0,
                                               const int* lastw, const float* lastc, void* out,
                                               const int* flag){
  if (*flag) final_body<true>(H,st0,lastw,lastc,out); else final_body<false>(H,st0,lastw,lastc,out);
}

extern "C" void kernel_launch(void* const* d_in, const int* in_sizes, int n_in,
                              void* d_out, int out_size, void* d_ws, size_t ws_size,
                              hipStream_t stream) {
  (void)in_sizes; (void)n_in; (void)out_size; (void)ws_size;
  const void* image = d_in[0];
  const int*  lact  = (const int*)d_in[1];
  const int*  pos   = (const int*)d_in[2];
  const void* done  = d_in[3];
  const void* st0   = d_in[4];
  const void* c1w = d_in[5];  const void* c1b = d_in[6];
  const void* c2w = d_in[7];  const void* c2b = d_in[8];
  const void* c3w = d_in[9];  const void* c3b = d_in[10];
  const void* fcw = d_in[11]; const void* fcb = d_in[12];
  const void* pw1 = d_in[13]; const void* pb1 = d_in[14];
  const void* pw2 = d_in[15]; const void* pb2 = d_in[16];
  const void* vw1 = d_in[17]; const void* vb1 = d_in[18];
  const void* vw2 = d_in[19]; const void* vb2 = d_in[20];
  char* ws = (char*)d_ws;

  // workspace (~54.1 MB). WT overlays A/Bv/C; DLT4 overlays PARTB (dead after k_yred).
  u16*   WT    = (u16*)  (ws + 0);           // 33,882,112
  u16*   A     = (u16*)  (ws + 0);
  u16*   Bv    = (u16*)  (ws + 14745600);
  u16*   C     = (u16*)  (ws + 19464192);
  float* H     = (float*)(ws + 33882368);    // 2,117,632
  float* YI    = (float*)(ws + 36000256);    // 16,384
  u16*   PARTB = (u16*)  (ws + 36016640);    // 8,388,608 (1024*4096 bf16)
  float* DLT4  = (float*)(ws + 36016640);    // 2,097,152 (overlays PARTB, used after yred)
  int*   PREV  = (int*)  (ws + 44405248);
  float* COEF  = (float*)(ws + 44409344);
  int*   LASTW = (int*)  (ws + 44413440);
  float* LASTC = (float*)(ws + 44446208);
  int*   FLAG  = (int*)  (ws + 44478976);
  u16*   W1F   = (u16*)  (ws + 44479232);    // 12,288
  u16*   W2F   = (u16*)  (ws + 44491520);    // 65,536
  u16*   W3F   = (u16*)  (ws + 44557056);    // 73,728
  u16*   FWF   = (u16*)  (ws + 44630784);    // 1,048,576 (MFMA B-frags of fcw)
  u16*   ST0T  = (u16*)  (ws + 45679360);    // 8,470,528 -> 54,149,888

  k_probe<<<1, 64, 0, stream>>>(image, FLAG);
  k_prep <<<684, 256, 0, stream>>>(c1w, c2w, c3w, fcw, st0, W1F, W2F, W3F, FWF, ST0T, FLAG);
  k_meta <<<36, 256, 0, stream>>>(pos, done, lact, PREV, COEF, H, LASTW, LASTC, FLAG);
  k_conv1<<<1024, 256, 0, stream>>>(image, W1F, c1b, A, FLAG);
  k_conv2<<<1024, 256, 0, stream>>>(A, W2F, c2b, Bv, FLAG);
  k_conv3<<<1024, 256, 0, stream>>>(Bv, W3F, c3b, C, FLAG);
  k_fc   <<<512, 256, 0, stream>>>(C, FWF, fcb, H, FLAG);
  k_wt   <<<1034, 256, 0, stream>>>(pw1, vw1, WT, FLAG);
  k_yinit<<<1024, 256, 0, stream>>>(ST0T, WT, PARTB);
  k_yred <<<64, 256, 0, stream>>>(PARTB, YI);
  k_delta<<<4096, 128, 0, stream>>>(H, WT, ST0T, pos, done, PREV, COEF, DLT4, FLAG);
  k_scan <<<32, 128, 0, stream>>>(YI, DLT4, done, pb1, vb1, pw2, pb2, vw2, vb2, d_out, FLAG);
  k_final<<<16544, 256, 0, stream>>>(H, st0, LASTW, LASTC, d_out, FLAG);
}

// Round 2
// 387.919 us; speedup vs baseline: 1.1225x; 1.0233x over previous
//
#include <hip/hip_runtime.h>

#define T_ 32
#define B_ 32
#define MAPD 517
#define P_ 256
#define FLATD (MAPD*P_)   // 132352
#define TBN (T_*B_)       // 1024

typedef unsigned short u16;
typedef unsigned int u32;
typedef __attribute__((ext_vector_type(4))) short short4v;
typedef __attribute__((ext_vector_type(8))) short short8v;
typedef __attribute__((ext_vector_type(4))) float f32x4;
typedef __attribute__((ext_vector_type(4))) u32 u32x4;

__device__ __forceinline__ float bfv(u16 u){ u32 x = ((u32)u)<<16; return __uint_as_float(x); }
__device__ __forceinline__ u16 fbf(float f){
  u32 x = __float_as_uint(f);
  return (u16)((x + 0x7fffu + ((x>>16)&1u))>>16);
}
template<bool F32> __device__ __forceinline__ float ld(const void* p, size_t i){
  if constexpr (F32) return ((const float*)p)[i];
  else               return bfv(((const u16*)p)[i]);
}

// ---- dtype probe: 1 if float inputs are fp32, 0 if bf16 ----
__global__ void k_probe(const void* img, int* flag){
  if (threadIdx.x == 0 && blockIdx.x == 0){
    const u16* u = (const u16*)img;
    int cnt = 0;
    for (int i = 0; i < 256; ++i) if (u[i] <= 0x4380u) ++cnt;
    *flag = (cnt < 240) ? 1 : 0;
  }
}

// ---- K-prep (fused): conv frag layouts + FWF (fc MFMA B-frags) + ST0T transpose ----
__global__ __launch_bounds__(256) void k_prep(const void* c1w, const void* c2w, const void* c3w,
                                              const void* fcw, const void* st0,
                                              u16* W1F, u16* W2F, u16* W3F, u16* FWF, u16* ST0T,
                                              const int* flag){
  __shared__ __align__(16) char smem_[32768];
  bool f32 = (*flag != 0);
  int bid = blockIdx.x, tid = threadIdx.x;
  if (bid < 24){
    int idx = bid*256 + tid;                   // 6144
    int j = idx & 7, l = (idx>>3) & 63, t = idx>>9;
    int nt = t/6, s = t - nt*6;
    int oc = nt*16 + (l&15);
    int kk = 8*(4*s + (l>>4)) + j;
    float v = f32 ? ((const float*)c1w)[oc*192+kk] : bfv(((const u16*)c1w)[oc*192+kk]);
    W1F[idx] = fbf(v);
  } else if (bid < 152){
    int idx = (bid-24)*256 + tid;              // 32768
    int j = idx & 7, l = (idx>>3) & 63, s = (idx>>9) & 15, nt = idx>>13;
    int oc = nt*16 + (l&15);
    int cin = (l>>4)*8 + j;
    int src = oc*512 + cin*16 + (s>>2)*4 + (s&3);
    float v = f32 ? ((const float*)c2w)[src] : bfv(((const u16*)c2w)[src]);
    W2F[idx] = fbf(v);
  } else if (bid < 296){
    int idx = (bid-152)*256 + tid;             // 36864
    int j = idx & 7, l = (idx>>3) & 63, t = idx>>9;   // t = nt*18+s
    int nt = t/18, s = t - nt*18;
    int oc = nt*16 + (l&15);
    int c = (s&1)*32 + (l>>4)*8 + j;
    int src = oc*576 + c*9 + (s>>1);
    float v = f32 ? ((const float*)c3w)[src] : bfv(((const u16*)c3w)[src]);
    W3F[idx] = fbf(v);
  } else if (bid < 424){
    // FWF: MFMA B-fragments of fc_w for k_fc.
    int b = bid - 296;                          // 128 blocks x 4096 elems
    for (int it = 0; it < 16; ++it){
      int idx = (b*16 + it)*256 + tid;          // 524288 total
      int j = idx & 7, l = (idx>>3) & 63, frag = idx >> 9;
      int nt = frag >> 5, kt = frag & 31;
      int kc = kt*32 + ((l>>4)<<3) + j;
      int kr = (kc & 63)*16 + (kc >> 6);
      int o  = nt*16 + (l & 15);
      float v = f32 ? ((const float*)fcw)[(size_t)o*1024 + kr]
                    : bfv(((const u16*)fcw)[(size_t)o*1024 + kr]);
      FWF[idx] = fbf(v);
    }
  } else {
    // ST0T[p][c][b] transpose
    u16* tile = (u16*)smem_;                   // 32,768 B
    int b0 = bid - 424;                        // 260 blocks
    int c0 = (b0 >> 2)*8, p0 = (b0 & 3)*64;
    for (int it = 0; it < 64; ++it){
      int idx = it*256 + tid;
      int pl = idx & 63, b = (idx>>6)&31, ci = idx>>11;
      int c = c0 + ci;
      float v = 0.f;
      if (c < MAPD)
        v = f32 ? ((const float*)st0)[((size_t)b*MAPD+c)*256 + p0+pl]
                : bfv(((const u16*)st0)[((size_t)b*MAPD+c)*256 + p0+pl]);
      tile[ci*2048 + pl*32 + b] = fbf(v);
    }
    __syncthreads();
    for (int it = 0; it < 64; ++it){
      int idx = it*256 + tid;
      int b = idx & 31, ci = (idx>>5)&7, pl = idx>>8;
      int c = c0 + ci;
      if (c < MAPD)
        ST0T[((size_t)(p0+pl)*MAPD + c)*32 + b] = tile[ci*2048 + pl*32 + b];
    }
  }
}

// ---- K-meta (fused): prev-writer/coef + one-hot into H ; last-writer/coef ----
__global__ void k_meta(const int* pos, const void* done, const int* lact,
                       int* prev, float* coef, float* H, int* lastw, float* lastc, const int* flag){
  bool f32 = (*flag != 0);
  int bid = blockIdx.x;
  if (bid < 4){
    int i = bid*256 + threadIdx.x;
    int t = i >> 5, b = i & 31;
    int p = pos[i*2]*16 + pos[i*2+1];
    int pv = -1;
    for (int s = t-1; s >= 0; --s){
      int n = s*32 + b;
      if (pos[n*2]*16 + pos[n*2+1] == p){ pv = s; break; }
    }
    float cf = 1.f;
    for (int s = (pv<0?0:pv+1); s <= t-1; ++s)
      cf *= (1.f - (f32 ? ((const float*)done)[s*32+b] : bfv(((const u16*)done)[s*32+b])));
    prev[i] = pv; coef[i] = cf;
    int la = lact[i];
    #pragma unroll
    for (int a = 0; a < 5; ++a) H[(size_t)i*MAPD + 512 + a] = (la == a) ? 1.f : 0.f;
  } else {
    int i = (bid-4)*256 + threadIdx.x;
    int b = i >> 8, p = i & 255;
    int lw = -1;
    for (int s = T_-1; s >= 0; --s){
      int n = s*32 + b;
      if (pos[n*2]*16 + pos[n*2+1] == p){ lw = s; break; }
    }
    float cf = 1.f;
    for (int s = (lw<0?0:lw+1); s < T_; ++s)
      cf *= (1.f - (f32 ? ((const float*)done)[s*32+b] : bfv(((const u16*)done)[s*32+b])));
    lastw[i] = lw; lastc[i] = cf;
  }
}

// ---- K1: conv1 MFMA implicit GEMM. M=225 (16 tiles), N=32 (2 tiles), K=192 (6 steps) ----
__global__ __launch_bounds__(256) void k_conv1(const void* img, const u16* W1F, const void* bias,
                                               u16* out, const int* flag){
  __shared__ u16 sImg[12288];
  __shared__ u16 sWF[6144];
  __shared__ float sB[32];
  bool f32 = (*flag != 0);
  int n = blockIdx.x, tid = threadIdx.x;
  if (f32){
    const float4* ip = (const float4*)((const float*)img + (size_t)n*12288);
    for (int i = tid; i < 3072; i += 256){
      float4 v = ip[i];
      ushort4 u; u.x = fbf(v.x); u.y = fbf(v.y); u.z = fbf(v.z); u.w = fbf(v.w);
      *(ushort4*)(sImg + i*4) = u;
    }
  } else {
    const ushort4* ip = (const ushort4*)((const u16*)img + (size_t)n*12288);
    for (int i = tid; i < 3072; i += 256) *(ushort4*)(sImg + i*4) = ip[i];
  }
  { const ushort4* wf = (const ushort4*)W1F;
    for (int i = tid; i < 1536; i += 256) *(ushort4*)(sWF + i*4) = wf[i]; }
  if (tid < 32) sB[tid] = f32 ? ((const float*)bias)[tid] : bfv(((const u16*)bias)[tid]);
  __syncthreads();

  int wv = tid >> 6, lane = tid & 63;
  int mi = lane & 15, q = lane >> 4;

  short8v bfr[2][6];
  #pragma unroll
  for (int nt = 0; nt < 2; ++nt)
    #pragma unroll
    for (int s = 0; s < 6; ++s)
      bfr[nt][s] = *(const short8v*)(sWF + ((nt*6+s)*64 + lane)*8);

  f32x4 acc[4][2];
  #pragma unroll
  for (int mt = 0; mt < 4; ++mt)
    #pragma unroll
    for (int nt = 0; nt < 2; ++nt)
      acc[mt][nt] = (f32x4){0.f,0.f,0.f,0.f};

  int base[4];
  #pragma unroll
  for (int mt = 0; mt < 4; ++mt){
    int m = (wv*4+mt)*16 + mi;
    int mc = m < 225 ? m : 224;
    int oy = mc/15, ox = mc - oy*15;
    base[mt] = oy*256 + ox*4;
  }

  for (int s = 0; s < 6; ++s){
    int cky = 4*s + q;
    int off = (cky >> 3)*4096 + (cky & 7)*64;
    #pragma unroll
    for (int mt = 0; mt < 4; ++mt){
      const u16* ap = sImg + base[mt] + off;
      short4v lo = *(const short4v*)ap;
      short4v hi = *(const short4v*)(ap + 4);
      short8v a = __builtin_shufflevector(lo, hi, 0,1,2,3,4,5,6,7);
      acc[mt][0] = __builtin_amdgcn_mfma_f32_16x16x32_bf16(a, bfr[0][s], acc[mt][0], 0,0,0);
      acc[mt][1] = __builtin_amdgcn_mfma_f32_16x16x32_bf16(a, bfr[1][s], acc[mt][1], 0,0,0);
    }
  }

  u16* ob = out + (size_t)n*7200;
  #pragma unroll
  for (int mt = 0; mt < 4; ++mt){
    int mrow0 = (wv*4+mt)*16 + q*4;
    #pragma unroll
    for (int nt = 0; nt < 2; ++nt){
      int oc = nt*16 + mi;
      float bv = sB[oc];
      #pragma unroll
      for (int r = 0; r < 4; ++r){
        int m = mrow0 + r;
        if (m < 225) ob[m*32 + oc] = fbf(fmaxf(acc[mt][nt][r] + bv, 0.f));
      }
    }
  }
}

// ---- K2: conv2 MFMA implicit GEMM ----
__global__ __launch_bounds__(256) void k_conv2(const u16* __restrict__ A, const u16* __restrict__ W2F,
                                               const void* bias, u16* __restrict__ out, const int* flag){
  __shared__ u16 sIn[7200];
  bool f32 = (*flag != 0);
  int n = blockIdx.x, tid = threadIdx.x;
  const ushort4* ip = (const ushort4*)(A + (size_t)n*7200);
  for (int i = tid; i < 1800; i += 256) *(ushort4*)(sIn + i*4) = ip[i];
  int wv = tid >> 6, lane = tid & 63, mi = lane & 15, q = lane >> 4;

  short8v bfr[16];
  #pragma unroll
  for (int s = 0; s < 16; ++s)
    bfr[s] = ((const short8v*)W2F)[(wv*16+s)*64 + lane];

  int oc = wv*16 + mi;
  float bv = f32 ? ((const float*)bias)[oc] : bfv(((const u16*)bias)[oc]);
  f32x4 acc[3];
  #pragma unroll
  for (int mt = 0; mt < 3; ++mt) acc[mt] = (f32x4){0.f,0.f,0.f,0.f};
  int base[3];
  #pragma unroll
  for (int mt = 0; mt < 3; ++mt){
    int m = mt*16 + mi; if (m > 35) m = 35;
    int oy = m/6, ox = m - oy*6;
    base[mt] = (oy*30 + ox*2)*32;
  }
  __syncthreads();
  #pragma unroll
  for (int s = 0; s < 16; ++s){
    int off = ((s>>2)*15 + (s&3))*32 + q*8;
    #pragma unroll
    for (int mt = 0; mt < 3; ++mt){
      short8v a = *(const short8v*)(sIn + base[mt] + off);
      acc[mt] = __builtin_amdgcn_mfma_f32_16x16x32_bf16(a, bfr[s], acc[mt], 0,0,0);
    }
  }
  u16* ob = out + (size_t)n*2304;
  #pragma unroll
  for (int mt = 0; mt < 3; ++mt)
    #pragma unroll
    for (int r = 0; r < 4; ++r){
      int m = mt*16 + q*4 + r;
      if (m < 36) ob[m*64 + oc] = fbf(fmaxf(acc[mt][r] + bv, 0.f));
    }
}

// ---- K3: conv3 MFMA implicit GEMM ----
__global__ __launch_bounds__(256) void k_conv3(const u16* __restrict__ Bv, const u16* __restrict__ W3F,
                                               const void* bias, u16* __restrict__ out, const int* flag){
  __shared__ u16 sIn[2304];
  bool f32 = (*flag != 0);
  int n = blockIdx.x, tid = threadIdx.x;
  const ushort4* ip = (const ushort4*)(Bv + (size_t)n*2304);
  for (int i = tid; i < 576; i += 256) *(ushort4*)(sIn + i*4) = ip[i];
  int wv = tid >> 6, lane = tid & 63, mi = lane & 15, q = lane >> 4;
  int oy = mi >> 2, ox = mi & 3;
  int oc = wv*16 + mi;
  float bv = f32 ? ((const float*)bias)[oc] : bfv(((const u16*)bias)[oc]);

  short8v bfr[18];
  #pragma unroll
  for (int s = 0; s < 18; ++s)
    bfr[s] = ((const short8v*)W3F)[(wv*18+s)*64 + lane];

  f32x4 acc = (f32x4){0.f,0.f,0.f,0.f};
  __syncthreads();
  #pragma unroll
  for (int s = 0; s < 18; ++s){
    int pair = s >> 1, ky = pair/3, kx = pair - ky*3;
    int off = ((oy+ky)*6 + ox+kx)*64 + (s&1)*32 + q*8;
    short8v a = *(const short8v*)(sIn + off);
    acc = __builtin_amdgcn_mfma_f32_16x16x32_bf16(a, bfr[s], acc, 0,0,0);
  }
  u16* ob = out + (size_t)n*1024;
  #pragma unroll
  for (int r = 0; r < 4; ++r)
    ob[(q*4+r)*64 + oc] = fbf(fmaxf(acc[r] + bv, 0.f));
}

// ---- K4: fc MFMA GEMM 1024x512x1024 + ReLU -> H[samp][517] fp32 ----
__global__ __launch_bounds__(256) void k_fc(const u16* __restrict__ C, const u16* __restrict__ FWF,
                                            const void* fb, float* __restrict__ H, const int* flag){
  bool f32 = (*flag != 0);
  int wv = threadIdx.x >> 6, lane = threadIdx.x & 63;
  int mi = lane & 15, q = lane >> 4;
  int mt = blockIdx.x >> 3;               // 0..63
  int nt = (blockIdx.x & 7)*4 + wv;       // 0..31
  const u16* ap = C + (size_t)(mt*16 + mi)*1024 + q*8;
  const short8v* bp = (const short8v*)FWF + (size_t)nt*32*64 + lane;
  f32x4 acc0 = (f32x4){0.f,0.f,0.f,0.f};
  f32x4 acc1 = (f32x4){0.f,0.f,0.f,0.f};
  #pragma unroll
  for (int kt = 0; kt < 32; kt += 2){
    short8v a0 = *(const short8v*)(ap + kt*32);
    short8v b0 = bp[kt*64];
    short8v a1 = *(const short8v*)(ap + (kt+1)*32);
    short8v b1 = bp[(kt+1)*64];
    acc0 = __builtin_amdgcn_mfma_f32_16x16x32_bf16(a0, b0, acc0, 0,0,0);
    acc1 = __builtin_amdgcn_mfma_f32_16x16x32_bf16(a1, b1, acc1, 0,0,0);
  }
  int o = nt*16 + mi;
  float bv = f32 ? ((const float*)fb)[o] : bfv(((const u16*)fb)[o]);
  #pragma unroll
  for (int r = 0; r < 4; ++r){
    int m = mt*16 + q*4 + r;
    H[(size_t)m*MAPD + o] = fmaxf(acc0[r] + acc1[r] + bv, 0.f);
  }
}

// ---- K0: transpose w1 (128 x 132352) into WT[p][c][j] bf16 ----
// Vectorized: 16B/lane global R/W, u32-paired LDS with XOR-swizzled 16B slots.
// LDS tile: element (pp, j-pair) at u32 tile[pp*64 + (((j>>3) ^ ((pp>>3)&15))<<2) + ((j>>1)&3)]
template<bool F32> __device__ void wt_body(const void* pw1, const void* vw1, u16* wt, u32* tile){
  int c  = blockIdx.x >> 1;
  int ph = blockIdx.x & 1;
  // phase 1: each lane loads rows j0=2*jp and j0+1, 8 consecutive pp -> 8 packed u32
  for (int it = 0; it < 4; ++it){
    int idx = it*256 + threadIdx.x;        // [0,1024)
    int jp = idx >> 4, pg = idx & 15;      // jp: 64 j-pairs, pg: 16 pp-groups of 8
    int j0 = jp*2;
    const void* w = (j0 < 64) ? pw1 : vw1;
    int jj0 = (j0 < 64) ? j0 : j0-64;
    size_t base0 = (size_t)jj0*FLATD + c*P_ + ph*128 + pg*8;
    size_t base1 = base0 + FLATD;
    u16 a[8], b[8];
    if constexpr (F32){
      const float* f = (const float*)w;
      float4 a0 = *(const float4*)(f + base0), a1 = *(const float4*)(f + base0 + 4);
      float4 b0 = *(const float4*)(f + base1), b1 = *(const float4*)(f + base1 + 4);
      a[0]=fbf(a0.x); a[1]=fbf(a0.y); a[2]=fbf(a0.z); a[3]=fbf(a0.w);
      a[4]=fbf(a1.x); a[5]=fbf(a1.y); a[6]=fbf(a1.z); a[7]=fbf(a1.w);
      b[0]=fbf(b0.x); b[1]=fbf(b0.y); b[2]=fbf(b0.z); b[3]=fbf(b0.w);
      b[4]=fbf(b1.x); b[5]=fbf(b1.y); b[6]=fbf(b1.z); b[7]=fbf(b1.w);
    } else {
      short8v va = *(const short8v*)((const u16*)w + base0);
      short8v vb = *(const short8v*)((const u16*)w + base1);
      #pragma unroll
      for (int k = 0; k < 8; ++k){ a[k] = (u16)va[k]; b[k] = (u16)vb[k]; }
    }
    int slot = (jp >> 2) ^ pg;             // pp>>3 == pg for all 8 rows of this lane
    int sub  = jp & 3;
    #pragma unroll
    for (int k = 0; k < 8; ++k){
      int pp = pg*8 + k;
      tile[pp*64 + slot*4 + sub] = (u32)a[k] | ((u32)b[k] << 16);
    }
  }
  __syncthreads();
  // phase 2: 16B LDS read (8 j) per lane, 256B-contiguous global writes
  for (int it = 0; it < 8; ++it){
    int idx = it*256 + threadIdx.x;        // [0,2048)
    int pp = idx >> 4, jb = idx & 15;
    int slot = jb ^ ((pp >> 3) & 15);
    u32x4 v = *(const u32x4*)(tile + pp*64 + slot*4);
    int p = ph*128 + pp;
    *(u32x4*)(wt + ((size_t)p*MAPD + c)*128 + jb*8) = v;
  }
}
__global__ __launch_bounds__(256) void k_wt(const void* pw1, const void* vw1, u16* wt, const int* flag){
  __shared__ u32 tile[128*64];             // 32 KB, swizzled
  if (*flag) wt_body<true>(pw1,vw1,wt,tile); else wt_body<false>(pw1,vw1,wt,tile);
}

// ---- K6: y_init partials: PARTB[block][b][j] (bf16), no atomics ----
template<int CLEN>
__device__ __forceinline__ void yloop(const u16* __restrict__ wp, const float* __restrict__ sSb,
                                      float (&acc)[8][2]){
  #pragma unroll 10
  for (int c = 0; c < CLEN; ++c){
    u32 w = *(const u32*)(wp + (size_t)c*128);            // global, 256 B/wave, L1-shared
    float w0 = bfv((u16)(w & 0xffffu)), w1 = bfv((u16)(w >> 16));
    const float4* s4 = (const float4*)(sSb + c*32);       // LDS broadcast (free)
    float4 sa = s4[0], sb = s4[1];
    float sv[8] = {sa.x,sa.y,sa.z,sa.w,sb.x,sb.y,sb.z,sb.w};
    #pragma unroll
    for (int bb = 0; bb < 8; ++bb){
      acc[bb][0] += sv[bb]*w0;
      acc[bb][1] += sv[bb]*w1;
    }
  }
}
__global__ __launch_bounds__(256) void k_yinit(const u16* __restrict__ ST0T, const u16* __restrict__ wt,
                                               u16* __restrict__ PARTB){
  __shared__ float sS[130*32];   // 16.6 KB -> high occupancy
  int p = blockIdx.x >> 2, cq = blockIdx.x & 3;
  int c0 = cq*130;
  int clen = (cq == 3) ? 127 : 130;
  const ushort4* ssrc = (const ushort4*)(ST0T + ((size_t)p*MAPD + c0)*32);
  int n4 = clen*8;
  for (int i = threadIdx.x; i < n4; i += 256){
    ushort4 u = ssrc[i];
    float4 f; f.x = bfv(u.x); f.y = bfv(u.y); f.z = bfv(u.z); f.w = bfv(u.w);
    *(float4*)(sS + i*4) = f;
  }
  __syncthreads();
  int jg = threadIdx.x & 63, bg = threadIdx.x >> 6;
  int j0 = jg*2, b0 = bg*8;
  const u16* wp = wt + ((size_t)p*MAPD + c0)*128 + j0;
  float acc[8][2] = {};
  if (cq < 3) yloop<130>(wp, sS + b0, acc);
  else        yloop<127>(wp, sS + b0, acc);
  u32* op = (u32*)(PARTB + (size_t)blockIdx.x*4096);
  #pragma unroll
  for (int bb = 0; bb < 8; ++bb){
    u32 pk = (u32)fbf(acc[bb][0]) | ((u32)fbf(acc[bb][1]) << 16);
    op[((b0+bb)*128 + j0) >> 1] = pk;
  }
}

// ---- K6b: reduce 1024 partials -> YI (fp32) ----
__global__ __launch_bounds__(256) void k_yred(const u16* __restrict__ PARTB, float* __restrict__ YI){
  int o = blockIdx.x*64 + (threadIdx.x & 63);
  int kq = threadIdx.x >> 6;
  float s = 0.f;
  const u16* pp = PARTB + (size_t)kq*256*4096 + o;
  #pragma unroll 8
  for (int k = 0; k < 256; ++k) s += bfv(pp[(size_t)k*4096]);
  __shared__ float red[256];
  red[threadIdx.x] = s;
  __syncthreads();
  if (threadIdx.x < 64)
    YI[o] = red[threadIdx.x] + red[threadIdx.x+64] + red[threadIdx.x+128] + red[threadIdx.x+192];
}

// ---- K7: delta partial dots; grid (n x 4 c-chunks) -> DLT4[n*4+cq][j] ----
__global__ __launch_bounds__(128) void k_delta(const float* __restrict__ H, const u16* __restrict__ wt,
                                               const u16* __restrict__ st0t,
                                               const int* __restrict__ pos, const void* done,
                                               const int* __restrict__ prev, const float* __restrict__ coef,
                                               float* __restrict__ dlt4, const int* flag){
  __shared__ float diff[132];
  bool f32 = (*flag != 0);
  int n = blockIdx.x >> 2, cq = blockIdx.x & 3;
  int c0 = cq*130, clen = (cq == 3) ? 127 : 130;
  int b = n & 31;
  int p = pos[n*2]*16 + pos[n*2+1];
  float dn = f32 ? ((const float*)done)[n] : bfv(((const u16*)done)[n]);
  float m = 1.f - dn;
  int pv = prev[n];
  float cf = coef[n]*m;
  const float* hc = H + (size_t)n*MAPD + c0;
  for (int c = threadIdx.x; c < clen; c += 128){
    float old;
    if (pv >= 0) old = H[(size_t)(pv*32 + b)*MAPD + c0 + c];
    else         old = bfv(st0t[((size_t)p*MAPD + c0 + c)*32 + b]);
    diff[c] = hc[c] - cf*old;
  }
  __syncthreads();
  int j = threadIdx.x;
  const u16* wp = wt + ((size_t)p*MAPD + c0)*128 + j;
  float acc = 0.f;
  int c = 0;
  for (; c + 4 <= clen; c += 4){
    u16 w0 = wp[(size_t)c*128], w1 = wp[(size_t)(c+1)*128];
    u16 w2 = wp[(size_t)(c+2)*128], w3 = wp[(size_t)(c+3)*128];
    acc += diff[c]*bfv(w0) + diff[c+1]*bfv(w1) + diff[c+2]*bfv(w2) + diff[c+3]*bfv(w3);
  }
  for (; c < clen; ++c) acc += diff[c]*bfv(wp[(size_t)c*128]);
  dlt4[(size_t)blockIdx.x*128 + j] = acc;
}

// ---- K8: 32-step scan + head matvecs (sums 4 delta partials) ----
template<bool F32> __device__ void scan_body(const float* yi, const float* dlt4, const void* done,
                                             const void* pb1, const void* vb1,
                                             const void* pw2, const void* pb2,
                                             const void* vw2, const void* vb2, void* out,
                                             float* th){
  int b = blockIdx.x, j = threadIdx.x;
  float y = yi[b*128 + j];
  float bias = (j < 64) ? ld<F32>(pb1, j) : ld<F32>(vb1, j-64);
  for (int t = 0; t < T_; ++t){
    int n = t*32 + b;
    float m = 1.f - ld<F32>(done, n);
    const float* dp = dlt4 + (size_t)n*4*128 + j;
    float d = dp[0] + dp[128] + dp[256] + dp[384];
    y = m*y + d;
    th[j] = tanhf(y + bias);
    __syncthreads();
    if (j < 5){
      float s = ld<F32>(pb2, j);
      for (int q = 0; q < 64; ++q) s += th[q]*ld<F32>(pw2, j*64 + q);
      if constexpr (F32) ((float*)out)[n*5 + j] = s; else ((u16*)out)[n*5 + j] = fbf(s);
    } else if (j == 5){
      float s = ld<F32>(vb2, 0);
      for (int q = 0; q < 64; ++q) s += th[64 + q]*ld<F32>(vw2, q);
      if constexpr (F32) ((float*)out)[5120 + n] = s; else ((u16*)out)[5120 + n] = fbf(s);
    }
    __syncthreads();
  }
}
__global__ __launch_bounds__(128) void k_scan(const float* yi, const float* dlt4, const void* done,
                                              const void* pb1, const void* vb1,
                                              const void* pw2, const void* pb2,
                                              const void* vw2, const void* vb2, void* out,
                                              const int* flag){
  __shared__ float th[128];
  if (*flag) scan_body<true>(yi,dlt4,done,pb1,vb1,pw2,pb2,vw2,vb2,out,th);
  else       scan_body<false>(yi,dlt4,done,pb1,vb1,pw2,pb2,vw2,vb2,out,th);
}

// ---- K9: final_state closed form ----
template<bool F32> __device__ void final_body(const float* H, const void* st0,
                                              const int* lastw, const float* lastc, void* out){
  size_t i = (size_t)blockIdx.x*256 + threadIdx.x;
  if (i >= (size_t)B_*FLATD) return;
  int b = (int)(i / FLATD);
  int r = (int)(i - (size_t)b*FLATD);
  int c = r >> 8, p = r & 255;
  int lw = lastw[b*256 + p];
  float lc = lastc[b*256 + p];
  float v;
  if (lw >= 0) v = H[(size_t)(lw*32 + b)*MAPD + c]*lc;
  else         v = ld<F32>(st0, i)*lc;
  if constexpr (F32) ((float*)out)[6144 + i] = v; else ((u16*)out)[6144 + i] = fbf(v);
}
__global__ __launch_bounds__(256) void k_final(const float* H, const void* st0,
                                               const int* lastw, const float* lastc, void* out,
                                               const int* flag){
  if (*flag) final_body<true>(H,st0,lastw,lastc,out); else final_body<false>(H,st0,lastw,lastc,out);
}

extern "C" void kernel_launch(void* const* d_in, const int* in_sizes, int n_in,
                              void* d_out, int out_size, void* d_ws, size_t ws_size,
                              hipStream_t stream) {
  (void)in_sizes; (void)n_in; (void)out_size; (void)ws_size;
  const void* image = d_in[0];
  const int*  lact  = (const int*)d_in[1];
  const int*  pos   = (const int*)d_in[2];
  const void* done  = d_in[3];
  const void* st0   = d_in[4];
  const void* c1w = d_in[5];  const void* c1b = d_in[6];
  const void* c2w = d_in[7];  const void* c2b = d_in[8];
  const void* c3w = d_in[9];  const void* c3b = d_in[10];
  const void* fcw = d_in[11]; const void* fcb = d_in[12];
  const void* pw1 = d_in[13]; const void* pb1 = d_in[14];
  const void* pw2 = d_in[15]; const void* pb2 = d_in[16];
  const void* vw1 = d_in[17]; const void* vb1 = d_in[18];
  const void* vw2 = d_in[19]; const void* vb2 = d_in[20];
  char* ws = (char*)d_ws;

  // workspace (~54.1 MB). WT overlays A/Bv/C; DLT4 overlays PARTB (dead after k_yred).
  u16*   WT    = (u16*)  (ws + 0);           // 33,882,112
  u16*   A     = (u16*)  (ws + 0);
  u16*   Bv    = (u16*)  (ws + 14745600);
  u16*   C     = (u16*)  (ws + 19464192);
  float* H     = (float*)(ws + 33882368);    // 2,117,632
  float* YI    = (float*)(ws + 36000256);    // 16,384
  u16*   PARTB = (u16*)  (ws + 36016640);    // 8,388,608 (1024*4096 bf16)
  float* DLT4  = (float*)(ws + 36016640);    // 2,097,152 (overlays PARTB, used after yred)
  int*   PREV  = (int*)  (ws + 44405248);
  float* COEF  = (float*)(ws + 44409344);
  int*   LASTW = (int*)  (ws + 44413440);
  float* LASTC = (float*)(ws + 44446208);
  int*   FLAG  = (int*)  (ws + 44478976);
  u16*   W1F   = (u16*)  (ws + 44479232);    // 12,288
  u16*   W2F   = (u16*)  (ws + 44491520);    // 65,536
  u16*   W3F   = (u16*)  (ws + 44557056);    // 73,728
  u16*   FWF   = (u16*)  (ws + 44630784);    // 1,048,576 (MFMA B-frags of fcw)
  u16*   ST0T  = (u16*)  (ws + 45679360);    // 8,470,528 -> 54,149,888

  k_probe<<<1, 64, 0, stream>>>(image, FLAG);
  k_prep <<<684, 256, 0, stream>>>(c1w, c2w, c3w, fcw, st0, W1F, W2F, W3F, FWF, ST0T, FLAG);
  k_meta <<<36, 256, 0, stream>>>(pos, done, lact, PREV, COEF, H, LASTW, LASTC, FLAG);
  k_conv1<<<1024, 256, 0, stream>>>(image, W1F, c1b, A, FLAG);
  k_conv2<<<1024, 256, 0, stream>>>(A, W2F, c2b, Bv, FLAG);
  k_conv3<<<1024, 256, 0, stream>>>(Bv, W3F, c3b, C, FLAG);
  k_fc   <<<512, 256, 0, stream>>>(C, FWF, fcb, H, FLAG);
  k_wt   <<<1034, 256, 0, stream>>>(pw1, vw1, WT, FLAG);
  k_yinit<<<1024, 256, 0, stream>>>(ST0T, WT, PARTB);
  k_yred <<<64, 256, 0, stream>>>(PARTB, YI);
  k_delta<<<4096, 128, 0, stream>>>(H, WT, ST0T, pos, done, PREV, COEF, DLT4, FLAG);
  k_scan <<<32, 128, 0, stream>>>(YI, DLT4, done, pb1, vb1, pw2, pb2, vw2, vb2, d_out, FLAG);
  k_final<<<16544, 256, 0, stream>>>(H, st0, LASTW, LASTC, d_out, FLAG);
}

// Round 3
// 363.829 us; speedup vs baseline: 1.1968x; 1.0662x over previous
//
#include <hip/hip_runtime.h>

#define T_ 32
#define B_ 32
#define MAPD 517
#define P_ 256
#define FLATD (MAPD*P_)   // 132352
#define TBN (T_*B_)       // 1024

typedef unsigned short u16;
typedef unsigned int u32;
typedef __attribute__((ext_vector_type(4))) short short4v;
typedef __attribute__((ext_vector_type(8))) short short8v;
typedef __attribute__((ext_vector_type(4))) float f32x4;
typedef __attribute__((ext_vector_type(2))) float f32x2;
typedef __attribute__((ext_vector_type(4))) u32 u32x4;

__device__ __forceinline__ float bfv(u16 u){ u32 x = ((u32)u)<<16; return __uint_as_float(x); }
__device__ __forceinline__ u16 fbf(float f){
  u32 x = __float_as_uint(f);
  return (u16)((x + 0x7fffu + ((x>>16)&1u))>>16);
}
template<bool F32> __device__ __forceinline__ float ld(const void* p, size_t i){
  if constexpr (F32) return ((const float*)p)[i];
  else               return bfv(((const u16*)p)[i]);
}

// ---- dtype probe: 1 if float inputs are fp32, 0 if bf16 ----
__global__ void k_probe(const void* img, int* flag){
  if (threadIdx.x == 0 && blockIdx.x == 0){
    const u16* u = (const u16*)img;
    int cnt = 0;
    for (int i = 0; i < 256; ++i) if (u[i] <= 0x4380u) ++cnt;
    *flag = (cnt < 240) ? 1 : 0;
  }
}

// ---- K-prep (fused): conv frag layouts + FWF (fc MFMA B-frags) + ST0T transpose ----
__global__ __launch_bounds__(256) void k_prep(const void* c1w, const void* c2w, const void* c3w,
                                              const void* fcw, const void* st0,
                                              u16* W1F, u16* W2F, u16* W3F, u16* FWF, u16* ST0T,
                                              const int* flag){
  __shared__ __align__(16) char smem_[32768];
  bool f32 = (*flag != 0);
  int bid = blockIdx.x, tid = threadIdx.x;
  if (bid < 24){
    int idx = bid*256 + tid;                   // 6144
    int j = idx & 7, l = (idx>>3) & 63, t = idx>>9;
    int nt = t/6, s = t - nt*6;
    int oc = nt*16 + (l&15);
    int kk = 8*(4*s + (l>>4)) + j;
    float v = f32 ? ((const float*)c1w)[oc*192+kk] : bfv(((const u16*)c1w)[oc*192+kk]);
    W1F[idx] = fbf(v);
  } else if (bid < 152){
    int idx = (bid-24)*256 + tid;              // 32768
    int j = idx & 7, l = (idx>>3) & 63, s = (idx>>9) & 15, nt = idx>>13;
    int oc = nt*16 + (l&15);
    int cin = (l>>4)*8 + j;
    int src = oc*512 + cin*16 + (s>>2)*4 + (s&3);
    float v = f32 ? ((const float*)c2w)[src] : bfv(((const u16*)c2w)[src]);
    W2F[idx] = fbf(v);
  } else if (bid < 296){
    int idx = (bid-152)*256 + tid;             // 36864
    int j = idx & 7, l = (idx>>3) & 63, t = idx>>9;   // t = nt*18+s
    int nt = t/18, s = t - nt*18;
    int oc = nt*16 + (l&15);
    int c = (s&1)*32 + (l>>4)*8 + j;
    int src = oc*576 + c*9 + (s>>1);
    float v = f32 ? ((const float*)c3w)[src] : bfv(((const u16*)c3w)[src]);
    W3F[idx] = fbf(v);
  } else if (bid < 424){
    // FWF: MFMA B-fragments of fc_w for k_fc.
    int b = bid - 296;                          // 128 blocks x 4096 elems
    for (int it = 0; it < 16; ++it){
      int idx = (b*16 + it)*256 + tid;          // 524288 total
      int j = idx & 7, l = (idx>>3) & 63, frag = idx >> 9;
      int nt = frag >> 5, kt = frag & 31;
      int kc = kt*32 + ((l>>4)<<3) + j;
      int kr = (kc & 63)*16 + (kc >> 6);
      int o  = nt*16 + (l & 15);
      float v = f32 ? ((const float*)fcw)[(size_t)o*1024 + kr]
                    : bfv(((const u16*)fcw)[(size_t)o*1024 + kr]);
      FWF[idx] = fbf(v);
    }
  } else {
    // ST0T[p][c][b] transpose
    u16* tile = (u16*)smem_;                   // 32,768 B
    int b0 = bid - 424;                        // 260 blocks
    int c0 = (b0 >> 2)*8, p0 = (b0 & 3)*64;
    for (int it = 0; it < 64; ++it){
      int idx = it*256 + tid;
      int pl = idx & 63, b = (idx>>6)&31, ci = idx>>11;
      int c = c0 + ci;
      float v = 0.f;
      if (c < MAPD)
        v = f32 ? ((const float*)st0)[((size_t)b*MAPD+c)*256 + p0+pl]
                : bfv(((const u16*)st0)[((size_t)b*MAPD+c)*256 + p0+pl]);
      tile[ci*2048 + pl*32 + b] = fbf(v);
    }
    __syncthreads();
    for (int it = 0; it < 64; ++it){
      int idx = it*256 + tid;
      int b = idx & 31, ci = (idx>>5)&7, pl = idx>>8;
      int c = c0 + ci;
      if (c < MAPD)
        ST0T[((size_t)(p0+pl)*MAPD + c)*32 + b] = tile[ci*2048 + pl*32 + b];
    }
  }
}

// ---- K-meta (fused): prev-writer/coef + one-hot into H ; last-writer/coef ----
__global__ void k_meta(const int* pos, const void* done, const int* lact,
                       int* prev, float* coef, float* H, int* lastw, float* lastc, const int* flag){
  bool f32 = (*flag != 0);
  int bid = blockIdx.x;
  if (bid < 4){
    int i = bid*256 + threadIdx.x;
    int t = i >> 5, b = i & 31;
    int p = pos[i*2]*16 + pos[i*2+1];
    int pv = -1;
    for (int s = t-1; s >= 0; --s){
      int n = s*32 + b;
      if (pos[n*2]*16 + pos[n*2+1] == p){ pv = s; break; }
    }
    float cf = 1.f;
    for (int s = (pv<0?0:pv+1); s <= t-1; ++s)
      cf *= (1.f - (f32 ? ((const float*)done)[s*32+b] : bfv(((const u16*)done)[s*32+b])));
    prev[i] = pv; coef[i] = cf;
    int la = lact[i];
    #pragma unroll
    for (int a = 0; a < 5; ++a) H[(size_t)i*MAPD + 512 + a] = (la == a) ? 1.f : 0.f;
  } else {
    int i = (bid-4)*256 + threadIdx.x;
    int b = i >> 8, p = i & 255;
    int lw = -1;
    for (int s = T_-1; s >= 0; --s){
      int n = s*32 + b;
      if (pos[n*2]*16 + pos[n*2+1] == p){ lw = s; break; }
    }
    float cf = 1.f;
    for (int s = (lw<0?0:lw+1); s < T_; ++s)
      cf *= (1.f - (f32 ? ((const float*)done)[s*32+b] : bfv(((const u16*)done)[s*32+b])));
    lastw[i] = lw; lastc[i] = cf;
  }
}

// ---- K123: fused conv1+conv2+conv3, intermediates in LDS, writes C ----
__global__ __launch_bounds__(256) void k_conv123(const void* img,
                                                 const u16* __restrict__ W1F, const void* b1,
                                                 const u16* __restrict__ W2F, const void* b2,
                                                 const u16* __restrict__ W3F, const void* b3,
                                                 u16* __restrict__ out, const int* flag){
  __shared__ u16 sImg[12288];   // 24576 B
  __shared__ u16 sA[7200];      // 14400 B (conv1 out: 225 x 32)
  __shared__ u16 sBv[2304];     //  4608 B (conv2 out: 36 x 64)
  bool f32 = (*flag != 0);
  int n = blockIdx.x, tid = threadIdx.x;
  // stage image -> bf16 LDS
  if (f32){
    const float4* ip = (const float4*)((const float*)img + (size_t)n*12288);
    for (int i = tid; i < 3072; i += 256){
      float4 v = ip[i];
      ushort4 u; u.x = fbf(v.x); u.y = fbf(v.y); u.z = fbf(v.z); u.w = fbf(v.w);
      *(ushort4*)(sImg + i*4) = u;
    }
  } else {
    const ushort4* ip = (const ushort4*)((const u16*)img + (size_t)n*12288);
    for (int i = tid; i < 3072; i += 256) *(ushort4*)(sImg + i*4) = ip[i];
  }
  int wv = tid >> 6, lane = tid & 63;
  int mi = lane & 15, q = lane >> 4;

  // ---- conv1: M=225 (16 tiles, 4/wave), N=32 (2 tiles), K=192 (6 steps) ----
  short8v bfr1[2][6];
  #pragma unroll
  for (int nt = 0; nt < 2; ++nt)
    #pragma unroll
    for (int s = 0; s < 6; ++s)
      bfr1[nt][s] = ((const short8v*)W1F)[(nt*6+s)*64 + lane];
  float b1v[2];
  #pragma unroll
  for (int nt = 0; nt < 2; ++nt)
    b1v[nt] = f32 ? ((const float*)b1)[nt*16+mi] : bfv(((const u16*)b1)[nt*16+mi]);
  __syncthreads();

  {
    f32x4 acc[4][2];
    #pragma unroll
    for (int mt = 0; mt < 4; ++mt)
      #pragma unroll
      for (int nt = 0; nt < 2; ++nt)
        acc[mt][nt] = (f32x4){0.f,0.f,0.f,0.f};
    int base[4];
    #pragma unroll
    for (int mt = 0; mt < 4; ++mt){
      int m = (wv*4+mt)*16 + mi;
      int mc = m < 225 ? m : 224;
      int oy = mc/15, ox = mc - oy*15;
      base[mt] = oy*256 + ox*4;
    }
    for (int s = 0; s < 6; ++s){
      int cky = 4*s + q;
      int off = (cky >> 3)*4096 + (cky & 7)*64;
      #pragma unroll
      for (int mt = 0; mt < 4; ++mt){
        const u16* ap = sImg + base[mt] + off;
        short4v lo = *(const short4v*)ap;
        short4v hi = *(const short4v*)(ap + 4);
        short8v a = __builtin_shufflevector(lo, hi, 0,1,2,3,4,5,6,7);
        acc[mt][0] = __builtin_amdgcn_mfma_f32_16x16x32_bf16(a, bfr1[0][s], acc[mt][0], 0,0,0);
        acc[mt][1] = __builtin_amdgcn_mfma_f32_16x16x32_bf16(a, bfr1[1][s], acc[mt][1], 0,0,0);
      }
    }
    #pragma unroll
    for (int mt = 0; mt < 4; ++mt){
      int mrow0 = (wv*4+mt)*16 + q*4;
      #pragma unroll
      for (int nt = 0; nt < 2; ++nt){
        int oc = nt*16 + mi;
        #pragma unroll
        for (int r = 0; r < 4; ++r){
          int m = mrow0 + r;
          if (m < 225) sA[m*32 + oc] = fbf(fmaxf(acc[mt][nt][r] + b1v[nt], 0.f));
        }
      }
    }
  }
  __syncthreads();

  // ---- conv2: M=36 (3 tiles), N=64 (wave-per-tile), K=512 (16 steps) ----
  {
    short8v bfr2[16];
    #pragma unroll
    for (int s = 0; s < 16; ++s)
      bfr2[s] = ((const short8v*)W2F)[(wv*16+s)*64 + lane];
    int oc = wv*16 + mi;
    float bv = f32 ? ((const float*)b2)[oc] : bfv(((const u16*)b2)[oc]);
    f32x4 acc[3];
    #pragma unroll
    for (int mt = 0; mt < 3; ++mt) acc[mt] = (f32x4){0.f,0.f,0.f,0.f};
    int base[3];
    #pragma unroll
    for (int mt = 0; mt < 3; ++mt){
      int m = mt*16 + mi; if (m > 35) m = 35;
      int oy = m/6, ox = m - oy*6;
      base[mt] = (oy*30 + ox*2)*32;
    }
    #pragma unroll
    for (int s = 0; s < 16; ++s){
      int off = ((s>>2)*15 + (s&3))*32 + q*8;
      #pragma unroll
      for (int mt = 0; mt < 3; ++mt){
        short8v a = *(const short8v*)(sA + base[mt] + off);
        acc[mt] = __builtin_amdgcn_mfma_f32_16x16x32_bf16(a, bfr2[s], acc[mt], 0,0,0);
      }
    }
    #pragma unroll
    for (int mt = 0; mt < 3; ++mt)
      #pragma unroll
      for (int r = 0; r < 4; ++r){
        int m = mt*16 + q*4 + r;
        if (m < 36) sBv[m*64 + oc] = fbf(fmaxf(acc[mt][r] + bv, 0.f));
      }
  }
  __syncthreads();

  // ---- conv3: M=16, N=64, K=576 (18 steps) ----
  {
    int oy = mi >> 2, ox = mi & 3;
    int oc = wv*16 + mi;
    float bv = f32 ? ((const float*)b3)[oc] : bfv(((const u16*)b3)[oc]);
    short8v bfr3[18];
    #pragma unroll
    for (int s = 0; s < 18; ++s)
      bfr3[s] = ((const short8v*)W3F)[(wv*18+s)*64 + lane];
    f32x4 acc = (f32x4){0.f,0.f,0.f,0.f};
    #pragma unroll
    for (int s = 0; s < 18; ++s){
      int pair = s >> 1, ky = pair/3, kx = pair - ky*3;
      int off = ((oy+ky)*6 + ox+kx)*64 + (s&1)*32 + q*8;
      short8v a = *(const short8v*)(sBv + off);
      acc = __builtin_amdgcn_mfma_f32_16x16x32_bf16(a, bfr3[s], acc, 0,0,0);
    }
    u16* ob = out + (size_t)n*1024;
    #pragma unroll
    for (int r = 0; r < 4; ++r)
      ob[(q*4+r)*64 + oc] = fbf(fmaxf(acc[r] + bv, 0.f));
  }
}

// ---- K4: fc MFMA GEMM 1024x512x1024 + ReLU -> H[samp][517] fp32 ----
__global__ __launch_bounds__(256) void k_fc(const u16* __restrict__ C, const u16* __restrict__ FWF,
                                            const void* fb, float* __restrict__ H, const int* flag){
  bool f32 = (*flag != 0);
  int wv = threadIdx.x >> 6, lane = threadIdx.x & 63;
  int mi = lane & 15, q = lane >> 4;
  int mt = blockIdx.x >> 3;               // 0..63
  int nt = (blockIdx.x & 7)*4 + wv;       // 0..31
  const u16* ap = C + (size_t)(mt*16 + mi)*1024 + q*8;
  const short8v* bp = (const short8v*)FWF + (size_t)nt*32*64 + lane;
  f32x4 acc0 = (f32x4){0.f,0.f,0.f,0.f};
  f32x4 acc1 = (f32x4){0.f,0.f,0.f,0.f};
  #pragma unroll
  for (int kt = 0; kt < 32; kt += 2){
    short8v a0 = *(const short8v*)(ap + kt*32);
    short8v b0 = bp[kt*64];
    short8v a1 = *(const short8v*)(ap + (kt+1)*32);
    short8v b1 = bp[(kt+1)*64];
    acc0 = __builtin_amdgcn_mfma_f32_16x16x32_bf16(a0, b0, acc0, 0,0,0);
    acc1 = __builtin_amdgcn_mfma_f32_16x16x32_bf16(a1, b1, acc1, 0,0,0);
  }
  int o = nt*16 + mi;
  float bv = f32 ? ((const float*)fb)[o] : bfv(((const u16*)fb)[o]);
  #pragma unroll
  for (int r = 0; r < 4; ++r){
    int m = mt*16 + q*4 + r;
    H[(size_t)m*MAPD + o] = fmaxf(acc0[r] + acc1[r] + bv, 0.f);
  }
}

// ---- K0: transpose w1 (128 x 132352) into WT[p][c][j] bf16 ----
template<bool F32> __device__ void wt_body(const void* pw1, const void* vw1, u16* wt, u32* tile){
  int c  = blockIdx.x >> 1;
  int ph = blockIdx.x & 1;
  for (int it = 0; it < 4; ++it){
    int idx = it*256 + threadIdx.x;        // [0,1024)
    int jp = idx >> 4, pg = idx & 15;      // jp: 64 j-pairs, pg: 16 pp-groups of 8
    int j0 = jp*2;
    const void* w = (j0 < 64) ? pw1 : vw1;
    int jj0 = (j0 < 64) ? j0 : j0-64;
    size_t base0 = (size_t)jj0*FLATD + c*P_ + ph*128 + pg*8;
    size_t base1 = base0 + FLATD;
    u16 a[8], b[8];
    if constexpr (F32){
      const float* f = (const float*)w;
      float4 a0 = *(const float4*)(f + base0), a1 = *(const float4*)(f + base0 + 4);
      float4 b0 = *(const float4*)(f + base1), b1 = *(const float4*)(f + base1 + 4);
      a[0]=fbf(a0.x); a[1]=fbf(a0.y); a[2]=fbf(a0.z); a[3]=fbf(a0.w);
      a[4]=fbf(a1.x); a[5]=fbf(a1.y); a[6]=fbf(a1.z); a[7]=fbf(a1.w);
      b[0]=fbf(b0.x); b[1]=fbf(b0.y); b[2]=fbf(b0.z); b[3]=fbf(b0.w);
      b[4]=fbf(b1.x); b[5]=fbf(b1.y); b[6]=fbf(b1.z); b[7]=fbf(b1.w);
    } else {
      short8v va = *(const short8v*)((const u16*)w + base0);
      short8v vb = *(const short8v*)((const u16*)w + base1);
      #pragma unroll
      for (int k = 0; k < 8; ++k){ a[k] = (u16)va[k]; b[k] = (u16)vb[k]; }
    }
    int slot = (jp >> 2) ^ pg;             // pp>>3 == pg for all 8 rows of this lane
    int sub  = jp & 3;
    #pragma unroll
    for (int k = 0; k < 8; ++k){
      int pp = pg*8 + k;
      tile[pp*64 + slot*4 + sub] = (u32)a[k] | ((u32)b[k] << 16);
    }
  }
  __syncthreads();
  for (int it = 0; it < 8; ++it){
    int idx = it*256 + threadIdx.x;        // [0,2048)
    int pp = idx >> 4, jb = idx & 15;
    int slot = jb ^ ((pp >> 3) & 15);
    u32x4 v = *(const u32x4*)(tile + pp*64 + slot*4);
    int p = ph*128 + pp;
    *(u32x4*)(wt + ((size_t)p*MAPD + c)*128 + jb*8) = v;
  }
}
__global__ __launch_bounds__(256) void k_wt(const void* pw1, const void* vw1, u16* wt, const int* flag){
  __shared__ u32 tile[128*64];             // 32 KB, swizzled
  if (*flag) wt_body<true>(pw1,vw1,wt,tile); else wt_body<false>(pw1,vw1,wt,tile);
}

// ---- K6: y_init partials: PARTB[block][b][j] (bf16), no atomics ----
template<int CLEN>
__device__ __forceinline__ void yloop(const u16* __restrict__ wp, const float* __restrict__ sSb,
                                      float (&acc)[8][2]){
  #pragma unroll 10
  for (int c = 0; c < CLEN; ++c){
    u32 w = *(const u32*)(wp + (size_t)c*128);            // global, 256 B/wave, L1-shared
    float w0 = bfv((u16)(w & 0xffffu)), w1 = bfv((u16)(w >> 16));
    const float4* s4 = (const float4*)(sSb + c*32);       // LDS broadcast (free)
    float4 sa = s4[0], sb = s4[1];
    float sv[8] = {sa.x,sa.y,sa.z,sa.w,sb.x,sb.y,sb.z,sb.w};
    #pragma unroll
    for (int bb = 0; bb < 8; ++bb){
      acc[bb][0] += sv[bb]*w0;
      acc[bb][1] += sv[bb]*w1;
    }
  }
}
__global__ __launch_bounds__(256) void k_yinit(const u16* __restrict__ ST0T, const u16* __restrict__ wt,
                                               u16* __restrict__ PARTB){
  __shared__ float sS[130*32];   // 16.6 KB -> high occupancy
  int p = blockIdx.x >> 2, cq = blockIdx.x & 3;
  int c0 = cq*130;
  int clen = (cq == 3) ? 127 : 130;
  const ushort4* ssrc = (const ushort4*)(ST0T + ((size_t)p*MAPD + c0)*32);
  int n4 = clen*8;
  for (int i = threadIdx.x; i < n4; i += 256){
    ushort4 u = ssrc[i];
    float4 f; f.x = bfv(u.x); f.y = bfv(u.y); f.z = bfv(u.z); f.w = bfv(u.w);
    *(float4*)(sS + i*4) = f;
  }
  __syncthreads();
  int jg = threadIdx.x & 63, bg = threadIdx.x >> 6;
  int j0 = jg*2, b0 = bg*8;
  const u16* wp = wt + ((size_t)p*MAPD + c0)*128 + j0;
  float acc[8][2] = {};
  if (cq < 3) yloop<130>(wp, sS + b0, acc);
  else        yloop<127>(wp, sS + b0, acc);
  u32* op = (u32*)(PARTB + (size_t)blockIdx.x*4096);
  #pragma unroll
  for (int bb = 0; bb < 8; ++bb){
    u32 pk = (u32)fbf(acc[bb][0]) | ((u32)fbf(acc[bb][1]) << 16);
    op[((b0+bb)*128 + j0) >> 1] = pk;
  }
}

// ---- K6b: reduce 1024 partials -> YI (fp32) ----
__global__ __launch_bounds__(256) void k_yred(const u16* __restrict__ PARTB, float* __restrict__ YI){
  int o = blockIdx.x*64 + (threadIdx.x & 63);
  int kq = threadIdx.x >> 6;
  float s = 0.f;
  const u16* pp = PARTB + (size_t)kq*256*4096 + o;
  #pragma unroll 8
  for (int k = 0; k < 256; ++k) s += bfv(pp[(size_t)k*4096]);
  __shared__ float red[256];
  red[threadIdx.x] = s;
  __syncthreads();
  if (threadIdx.x < 64)
    YI[o] = red[threadIdx.x] + red[threadIdx.x+64] + red[threadIdx.x+128] + red[threadIdx.x+192];
}

// ---- K7: delta partial dots; grid (n x 4 c-chunks), j-paired u32 loads,
//      block's two waves split the c-chunk -> DLT8[(n*4+cq)*2+half][j] ----
__global__ __launch_bounds__(128) void k_delta(const float* __restrict__ H, const u16* __restrict__ wt,
                                               const u16* __restrict__ st0t,
                                               const int* __restrict__ pos, const void* done,
                                               const int* __restrict__ prev, const float* __restrict__ coef,
                                               float* __restrict__ dlt8, const int* flag){
  __shared__ float diff[132];
  bool f32 = (*flag != 0);
  int n = blockIdx.x >> 2, cq = blockIdx.x & 3;
  int c0 = cq*130, clen = (cq == 3) ? 127 : 130;
  int b = n & 31;
  int p = pos[n*2]*16 + pos[n*2+1];
  float dn = f32 ? ((const float*)done)[n] : bfv(((const u16*)done)[n]);
  float m = 1.f - dn;
  int pv = prev[n];
  float cf = coef[n]*m;
  const float* hc = H + (size_t)n*MAPD + c0;
  for (int c = threadIdx.x; c < clen; c += 128){
    float old;
    if (pv >= 0) old = H[(size_t)(pv*32 + b)*MAPD + c0 + c];
    else         old = bfv(st0t[((size_t)p*MAPD + c0 + c)*32 + b]);
    diff[c] = hc[c] - cf*old;
  }
  __syncthreads();
  int half = threadIdx.x >> 6, jp = threadIdx.x & 63, j0 = jp*2;
  int hbase, hlen;
  if (cq == 3){ hbase = half*64; hlen = half ? 63 : 64; }
  else        { hbase = half*65; hlen = 65; }
  const u16* wp = wt + ((size_t)p*MAPD + c0 + hbase)*128 + j0;
  const float* dptr = diff + hbase;
  float a0 = 0.f, a1 = 0.f;
  int c = 0;
  for (; c + 4 <= hlen; c += 4){
    u32 w0 = *(const u32*)(wp + (size_t)(c+0)*128);
    u32 w1 = *(const u32*)(wp + (size_t)(c+1)*128);
    u32 w2 = *(const u32*)(wp + (size_t)(c+2)*128);
    u32 w3 = *(const u32*)(wp + (size_t)(c+3)*128);
    float d0 = dptr[c], d1 = dptr[c+1], d2 = dptr[c+2], d3 = dptr[c+3];
    a0 += d0*bfv((u16)(w0 & 0xffffu)) + d1*bfv((u16)(w1 & 0xffffu))
        + d2*bfv((u16)(w2 & 0xffffu)) + d3*bfv((u16)(w3 & 0xffffu));
    a1 += d0*bfv((u16)(w0 >> 16)) + d1*bfv((u16)(w1 >> 16))
        + d2*bfv((u16)(w2 >> 16)) + d3*bfv((u16)(w3 >> 16));
  }
  for (; c < hlen; ++c){
    u32 w = *(const u32*)(wp + (size_t)c*128);
    a0 += dptr[c]*bfv((u16)(w & 0xffffu));
    a1 += dptr[c]*bfv((u16)(w >> 16));
  }
  f32x2 st; st[0] = a0; st[1] = a1;
  *(f32x2*)(dlt8 + ((size_t)blockIdx.x*2 + half)*128 + j0) = st;
}

// ---- K8a: barrier-free 32-step scan -> TH[n][128] fp32 ----
__global__ __launch_bounds__(128) void k_scan(const float* __restrict__ yi,
                                              const float* __restrict__ dlt8, const void* done,
                                              const void* pb1, const void* vb1,
                                              float* __restrict__ TH, const int* flag){
  bool f32 = (*flag != 0);
  int b = blockIdx.x, j = threadIdx.x;
  float y = yi[b*128 + j];
  float bias = (j < 64) ? (f32 ? ((const float*)pb1)[j]    : bfv(((const u16*)pb1)[j]))
                        : (f32 ? ((const float*)vb1)[j-64] : bfv(((const u16*)vb1)[j-64]));
  for (int t = 0; t < T_; ++t){
    int n = t*32 + b;
    float m = 1.f - (f32 ? ((const float*)done)[n] : bfv(((const u16*)done)[n]));
    const float* dp = dlt8 + (size_t)n*1024 + j;
    float d = dp[0] + dp[128] + dp[256] + dp[384]
            + dp[512] + dp[640] + dp[768] + dp[896];
    y = m*y + d;
    TH[(size_t)n*128 + j] = tanhf(y + bias);
  }
}

// ---- K8b: head matvecs from TH (wave per sample, shuffle reduce) ----
__global__ __launch_bounds__(256) void k_heads(const float* __restrict__ TH,
                                               const void* pw2, const void* pb2,
                                               const void* vw2, const void* vb2,
                                               void* out, const int* flag){
  bool f32 = (*flag != 0);
  int wv = threadIdx.x >> 6, lane = threadIdx.x & 63;
  int n = blockIdx.x*4 + wv;
  const float* th = TH + (size_t)n*128;
  float tq = th[lane];
  float tv = th[64 + lane];
  float acc[6];
  #pragma unroll
  for (int j = 0; j < 5; ++j)
    acc[j] = tq * (f32 ? ((const float*)pw2)[j*64 + lane] : bfv(((const u16*)pw2)[j*64 + lane]));
  acc[5] = tv * (f32 ? ((const float*)vw2)[lane] : bfv(((const u16*)vw2)[lane]));
  #pragma unroll
  for (int off = 32; off > 0; off >>= 1)
    #pragma unroll
    for (int j = 0; j < 6; ++j)
      acc[j] += __shfl_down(acc[j], off, 64);
  if (lane == 0){
    #pragma unroll
    for (int j = 0; j < 5; ++j){
      float s = acc[j] + (f32 ? ((const float*)pb2)[j] : bfv(((const u16*)pb2)[j]));
      if (f32) ((float*)out)[n*5 + j] = s; else ((u16*)out)[n*5 + j] = fbf(s);
    }
    float s = acc[5] + (f32 ? ((const float*)vb2)[0] : bfv(((const u16*)vb2)[0]));
    if (f32) ((float*)out)[5120 + n] = s; else ((u16*)out)[5120 + n] = fbf(s);
  }
}

// ---- K9: final_state closed form ----
template<bool F32> __device__ void final_body(const float* H, const void* st0,
                                              const int* lastw, const float* lastc, void* out){
  size_t i = (size_t)blockIdx.x*256 + threadIdx.x;
  if (i >= (size_t)B_*FLATD) return;
  int b = (int)(i / FLATD);
  int r = (int)(i - (size_t)b*FLATD);
  int c = r >> 8, p = r & 255;
  int lw = lastw[b*256 + p];
  float lc = lastc[b*256 + p];
  float v;
  if (lw >= 0) v = H[(size_t)(lw*32 + b)*MAPD + c]*lc;
  else         v = ld<F32>(st0, i)*lc;
  if constexpr (F32) ((float*)out)[6144 + i] = v; else ((u16*)out)[6144 + i] = fbf(v);
}
__global__ __launch_bounds__(256) void k_final(const float* H, const void* st0,
                                               const int* lastw, const float* lastc, void* out,
                                               const int* flag){
  if (*flag) final_body<true>(H,st0,lastw,lastc,out); else final_body<false>(H,st0,lastw,lastc,out);
}

extern "C" void kernel_launch(void* const* d_in, const int* in_sizes, int n_in,
                              void* d_out, int out_size, void* d_ws, size_t ws_size,
                              hipStream_t stream) {
  (void)in_sizes; (void)n_in; (void)out_size; (void)ws_size;
  const void* image = d_in[0];
  const int*  lact  = (const int*)d_in[1];
  const int*  pos   = (const int*)d_in[2];
  const void* done  = d_in[3];
  const void* st0   = d_in[4];
  const void* c1w = d_in[5];  const void* c1b = d_in[6];
  const void* c2w = d_in[7];  const void* c2b = d_in[8];
  const void* c3w = d_in[9];  const void* c3b = d_in[10];
  const void* fcw = d_in[11]; const void* fcb = d_in[12];
  const void* pw1 = d_in[13]; const void* pb1 = d_in[14];
  const void* pw2 = d_in[15]; const void* pb2 = d_in[16];
  const void* vw1 = d_in[17]; const void* vb1 = d_in[18];
  const void* vw2 = d_in[19]; const void* vb2 = d_in[20];
  char* ws = (char*)d_ws;

  // workspace (~54.7 MB). WT overlays C; DLT8 overlays PARTB (dead after k_yred).
  u16*   WT    = (u16*)  (ws + 0);           // 33,882,112
  u16*   C     = (u16*)  (ws + 19464192);    // 2,097,152 (overlays WT tail region used later)
  float* H     = (float*)(ws + 33882368);    // 2,117,632
  float* YI    = (float*)(ws + 36000256);    // 16,384
  u16*   PARTB = (u16*)  (ws + 36016640);    // 8,388,608 (1024*4096 bf16)
  float* DLT8  = (float*)(ws + 36016640);    // 4,194,304 (overlays PARTB, used after yred)
  int*   PREV  = (int*)  (ws + 44405248);
  float* COEF  = (float*)(ws + 44409344);
  int*   LASTW = (int*)  (ws + 44413440);
  float* LASTC = (float*)(ws + 44446208);
  int*   FLAG  = (int*)  (ws + 44478976);
  u16*   W1F   = (u16*)  (ws + 44479232);    // 12,288
  u16*   W2F   = (u16*)  (ws + 44491520);    // 65,536
  u16*   W3F   = (u16*)  (ws + 44557056);    // 73,728
  u16*   FWF   = (u16*)  (ws + 44630784);    // 1,048,576 (MFMA B-frags of fcw)
  u16*   ST0T  = (u16*)  (ws + 45679360);    // 8,470,528
  float* TH    = (float*)(ws + 54149888);    // 524,288 -> 54,674,176

  k_probe<<<1, 64, 0, stream>>>(image, FLAG);
  k_prep <<<684, 256, 0, stream>>>(c1w, c2w, c3w, fcw, st0, W1F, W2F, W3F, FWF, ST0T, FLAG);
  k_meta <<<36, 256, 0, stream>>>(pos, done, lact, PREV, COEF, H, LASTW, LASTC, FLAG);
  k_conv123<<<1024, 256, 0, stream>>>(image, W1F, c1b, W2F, c2b, W3F, c3b, C, FLAG);
  k_fc   <<<512, 256, 0, stream>>>(C, FWF, fcb, H, FLAG);
  k_wt   <<<1034, 256, 0, stream>>>(pw1, vw1, WT, FLAG);
  k_yinit<<<1024, 256, 0, stream>>>(ST0T, WT, PARTB);
  k_yred <<<64, 256, 0, stream>>>(PARTB, YI);
  k_delta<<<4096, 128, 0, stream>>>(H, WT, ST0T, pos, done, PREV, COEF, DLT8, FLAG);
  k_scan <<<32, 128, 0, stream>>>(YI, DLT8, done, pb1, vb1, TH, FLAG);
  k_heads<<<256, 256, 0, stream>>>(TH, pw2, pb2, vw2, vb2, d_out, FLAG);
  k_final<<<16544, 256, 0, stream>>>(H, st0, LASTW, LASTC, d_out, FLAG);
}